// Round 16
// baseline (71.289 us; speedup 1.0000x reference)
//
#include <hip/hip_runtime.h>
#include <hip/hip_bf16.h>

#define NFFT    1024
#define HOPSZ   256
#define XLEN    262144
#define PADLEN  (XLEN + NFFT)      // 263168
#define NBATCH  16
#define NBINS2  1026
#define FBIN    513
#define NFRAMES 1025
#define NGF     (NBATCH * NFRAMES) // 16400
#define TOTOUT  ((size_t)NBATCH * FBIN * NFRAMES)

// GEMM geometry: 128 bins x 128 gf per block, BK=64, 4 waves (2 bin-halves x 2 gf-halves)
#define KT 64
#define NKT 16
#define NWG 1024                   // 8 mt x 128 nt
#define BUFE 16384                 // elems per buffer: W 128x64 + X 128x64
#define BUFB 32768                 // bytes per buffer
#define LDS_BYTES (2 * BUFB)       // 65536 -> 2 blocks/CU
#define NTAIL  49184               // 2*16400 + 16*1024 = 6148 * 8
#define TAIL_BLKS (NTAIL / 8)      // 6148
#define PSTRIDE 132

// fused pack kernel block ranges
#define PX_BLKS 2056               // NBATCH*PADLEN/8/256
#define PW_BLKS 1026               // NBINS2*NFFT/4/256

typedef short bf16x8 __attribute__((ext_vector_type(8)));
typedef float f32x4  __attribute__((ext_vector_type(4)));
typedef unsigned short u16x8 __attribute__((ext_vector_type(8)));
typedef unsigned short u16x4 __attribute__((ext_vector_type(4)));

__device__ __forceinline__ unsigned short f2bf(float f) {
  union { float f; unsigned u; } v; v.f = f;
  unsigned r = v.u + 0x7fffu + ((v.u >> 16) & 1u);   // RNE
  return (unsigned short)(r >> 16);
}
__device__ __forceinline__ float bf2f(unsigned short h) {
  union { unsigned u; float f; } v; v.u = ((unsigned)h) << 16; return v.f;
}

typedef __attribute__((address_space(1))) void void_g;
typedef __attribute__((address_space(3))) void void_l;
__device__ __forceinline__ void gload_lds16(const void* g, void* l) {
  __builtin_amdgcn_global_load_lds((void_g*)(g), (void_l*)(l), 16, 0, 0);
}

// ---- fused pack: x -> bf16 (padded) | W -> bf16 ----
__global__ __launch_bounds__(256) void pack_kernel(const float* __restrict__ x,
                                                   const float* __restrict__ W,
                                                   unsigned short* __restrict__ xp,
                                                   unsigned short* __restrict__ wb) {
  const int bid = blockIdx.x;
  const int tid = threadIdx.x;
  if (bid < PX_BLKS) {
    long long base = ((long long)bid * 256 + tid) * 8;
    int b   = (int)(base / PADLEN);
    int pos = (int)(base % PADLEN);
    const float* xb = x + (long long)b * XLEN;
    u16x8 v;
#pragma unroll
    for (int j = 0; j < 8; ++j) {
      int xi = pos + j - (NFFT / 2);
      float f = ((unsigned)xi < (unsigned)XLEN) ? xb[xi] : 0.0f;
      v[j] = f2bf(f);
    }
    *reinterpret_cast<u16x8*>(xp + base) = v;
  } else {
    long long t = (((long long)(bid - PX_BLKS)) * 256 + tid) * 4;
    float4 f = *reinterpret_cast<const float4*>(W + t);
    u16x4 v;
    v[0] = f2bf(f.x); v[1] = f2bf(f.y); v[2] = f2bf(f.z); v[3] = f2bf(f.w);
    *reinterpret_cast<u16x4*>(wb + t) = v;
  }
}

// ---- 128x128 GEMM (r14-proven) + fused tail blocks (bid >= NWG) ----
__global__ __launch_bounds__(256, 2) void stft_mfma128_kernel(const unsigned short* __restrict__ Xp,
                                                              const unsigned short* __restrict__ Wb,
                                                              float* __restrict__ out) {
  const int bid = blockIdx.x;
  const int tid = threadIdx.x;
  const int l   = tid & 63;

  if (bid >= NWG) {
    // ---- tail path: 4 waves x 2 outputs, wave-per-output shuffle reduce ----
    const int wbase = (bid - NWG) * 8 + (tid >> 6) * 2;
#pragma unroll
    for (int it = 0; it < 2; ++it) {
      const int wid = wbase + it;
      int bin, gf;
      if (wid < 2 * NGF) { bin = 1024 + (wid & 1); gf = wid >> 1; }
      else { const int s = wid - 2 * NGF; gf = 16384 + (s & 15); bin = s >> 4; }
      const int bb = gf / NFRAMES;
      const int fr = gf - bb * NFRAMES;
      const unsigned short* xr = Xp + (size_t)bb * PADLEN + (size_t)fr * HOPSZ + l * 16;
      const unsigned short* wr = Wb + (size_t)bin * NFFT + l * 16;
      u16x8 x0 = *reinterpret_cast<const u16x8*>(xr);
      u16x8 x1 = *reinterpret_cast<const u16x8*>(xr + 8);
      u16x8 w0 = *reinterpret_cast<const u16x8*>(wr);
      u16x8 w1 = *reinterpret_cast<const u16x8*>(wr + 8);
      float s0 = 0.f, s1 = 0.f;
#pragma unroll
      for (int j = 0; j < 8; ++j) {
        s0 = fmaf(bf2f(x0[j]), bf2f(w0[j]), s0);
        s1 = fmaf(bf2f(x1[j]), bf2f(w1[j]), s1);
      }
      float s = s0 + s1;
#pragma unroll
      for (int k = 32; k >= 1; k >>= 1) s += __shfl_xor(s, k);
      if (l == 0) {
        size_t off;
        if (bin < FBIN) off = ((size_t)bb * FBIN + bin) * NFRAMES + fr;
        else            off = TOTOUT + ((size_t)bb * FBIN + (bin - FBIN)) * NFRAMES + fr;
        out[off] = s;
      }
    }
    return;
  }

  // ---- GEMM path (r14 verbatim) ----
  extern __shared__ unsigned short lds[];
  const int w   = tid >> 6;        // 0..3
  const int wr  = w >> 1;          // bin half (64 bins)
  const int wc  = w & 1;           // gf half (64 frames)
  const int r16 = l & 15, hi = l >> 4;

  // XCD swizzle: each XCD owns all 8 mt x 16 nt; consecutive blocks vary mt
  const int xcd   = bid & 7;
  const int local = bid >> 3;           // 0..127
  const int nt    = xcd * 16 + (local >> 3);
  const int mt    = local & 7;
  const int bin0  = mt * 128;
  const int gf0   = nt * 128;

  // staging (pre-swizzled global source)
  const int lr = l >> 3;
  const int ls = l & 7;
  const int cswz = ((ls ^ lr) << 3);

  unsigned aqoff[4], boff[4];
#pragma unroll
  for (int q = 0; q < 4; ++q)
    aqoff[q] = (unsigned)(bin0 + (w * 4 + q) * 8 + lr) * NFFT + cswz;
#pragma unroll
  for (int j = 0; j < 4; ++j) {
    const int gf = gf0 + (w * 4 + j) * 8 + lr;     // < 16384
    const int bb = gf / NFRAMES;
    const int fr = gf - bb * NFRAMES;
    boff[j] = (unsigned)bb * PADLEN + (unsigned)fr * HOPSZ + cswz;
  }

#define STAGE(D, KC) do { \
    _Pragma("unroll") \
    for (int q_ = 0; q_ < 4; ++q_) \
      gload_lds16(Wb + aqoff[q_] + (KC), lds + (D) * BUFE + (w * 4 + q_) * 512); \
    _Pragma("unroll") \
    for (int j_ = 0; j_ < 4; ++j_) \
      gload_lds16(Xp + boff[j_] + (KC), lds + (D) * BUFE + 8192 + (w * 4 + j_) * 512); \
    } while (0)

  // fragment read bases (T2 XOR-swizzle, 128B rows, 8x16B slots)
  const int aB0 = (wr * 64 + r16) * 128;
  const int bB0 = 16384 + (wc * 64 + r16) * 128;
  const int swz = (r16 & 7) << 4;
  const int c0  = (hi * 16) ^ swz;
  const int c1  = (64 + hi * 16) ^ swz;

#define RD8(BASE, C, AARR, BARR) do { \
    _Pragma("unroll") \
    for (int n_ = 0; n_ < 4; ++n_) \
      BARR[n_] = *reinterpret_cast<const bf16x8*>((const char*)(BASE) + bB0 + n_ * 2048 + (C)); \
    _Pragma("unroll") \
    for (int m_ = 0; m_ < 4; ++m_) \
      AARR[m_] = *reinterpret_cast<const bf16x8*>((const char*)(BASE) + aB0 + m_ * 2048 + (C)); \
    } while (0)

#define MFMA16(AARR, BARR) do { \
    __builtin_amdgcn_s_setprio(1); \
    _Pragma("unroll") \
    for (int m_ = 0; m_ < 4; ++m_) { \
      _Pragma("unroll") \
      for (int n_ = 0; n_ < 4; ++n_) \
        acc[m_][n_] = __builtin_amdgcn_mfma_f32_16x16x32_bf16(AARR[m_], BARR[n_], acc[m_][n_], 0, 0, 0); \
    } \
    __builtin_amdgcn_s_setprio(0); } while (0)

  f32x4 acc[4][4] = {};
  bf16x8 A0[4], B0[4], A1[4], B1[4];

  // ---- prologue: stage kt0->buf0, kt1->buf1; kt0 visible; read (buf0,ks0) ----
  STAGE(0, 0);
  STAGE(1, KT);
  asm volatile("s_waitcnt vmcnt(8)" ::: "memory");
  __builtin_amdgcn_s_barrier();
  __builtin_amdgcn_sched_barrier(0);
  RD8(lds, c0, A0, B0);

#pragma unroll 1
  for (int t = 0; t < NKT; ++t) {
    const int ci = t & 1;
    const char* cbuf = (const char*)lds + ci * BUFB;
    const char* nbuf = (const char*)lds + (ci ^ 1) * BUFB;
    const int kc2 = (t + 2) << 6;

    // phase A: read (cbuf, ks1) ahead; counted wait; MFMA ks0
    RD8(cbuf, c1, A1, B1);
    __builtin_amdgcn_sched_barrier(0);
    asm volatile("s_waitcnt lgkmcnt(8)" ::: "memory");
    __builtin_amdgcn_sched_barrier(0);
    MFMA16(A0, B0);

    // phase B: drain own reads+stages BEFORE barrier (cross-wave safety);
    // barrier; next-tile reads + kt+2 stages under MFMA ks1
    asm volatile("s_waitcnt vmcnt(0) lgkmcnt(0)" ::: "memory");
    __builtin_amdgcn_sched_barrier(0);
    __builtin_amdgcn_s_barrier();
    __builtin_amdgcn_sched_barrier(0);
    if (t < NKT - 1) RD8(nbuf, c0, A0, B0);
    if (t < NKT - 2) STAGE(ci, kc2);
    __builtin_amdgcn_sched_barrier(0);
    MFMA16(A1, B1);
  }

  // ---- epilogue: 2 chunks of 64 bin-rows; LDS patch; 256B-contiguous streams ----
  {
    float* patch = (float*)lds;
    const int col   = l & 15;
    const int rbase = (l >> 4) * 4;
    const int colbase = wc * 64;

    size_t baseR[2];
#pragma unroll
    for (int j = 0; j < 2; ++j) {
      const int gf = gf0 + j * 64 + l;
      const int bb = gf / NFRAMES;
      const int fr = gf - bb * NFRAMES;
      baseR[j] = (size_t)bb * FBIN * NFRAMES + fr;
    }

#pragma unroll
    for (int c = 0; c < 2; ++c) {
      __builtin_amdgcn_s_barrier();
      if (wr == c) {
#pragma unroll
        for (int m = 0; m < 4; ++m)
#pragma unroll
          for (int n = 0; n < 4; ++n)
#pragma unroll
            for (int r = 0; r < 4; ++r)
              patch[(m * 16 + rbase + r) * PSTRIDE + colbase + n * 16 + col] = acc[m][n][r];
      }
      __builtin_amdgcn_s_barrier();

      for (int i = 0; i < 16; ++i) {
        const int row = i * 4 + w;
        const int bin = bin0 + c * 64 + row;
        const size_t binoff = (size_t)bin * NFRAMES;
#pragma unroll
        for (int j = 0; j < 2; ++j) {
          const float v = patch[row * PSTRIDE + j * 64 + l];
          size_t off = binoff + (bin < FBIN ? baseR[j]
                                            : baseR[j] + TOTOUT - (size_t)FBIN * NFRAMES);
          out[off] = v;
        }
      }
    }
  }
#undef STAGE
#undef RD8
#undef MFMA16
}

// ---- exact f32 direct kernel: fallback only ----
__global__ void stft_direct_kernel(const float* __restrict__ x, const float* __restrict__ W,
                                   float* __restrict__ out,
                                   int bin_lo, int nbins, int fr_lo, int nframes) {
  long long total = (long long)NBATCH * nbins * nframes;
  for (long long t = (long long)blockIdx.x * blockDim.x + threadIdx.x; t < total;
       t += (long long)gridDim.x * blockDim.x) {
    int fr = fr_lo + (int)(t % nframes);
    long long q = t / nframes;
    int bin = bin_lo + (int)(q % nbins);
    int b   = (int)(q / nbins);
    const float* xb = x + (long long)b * XLEN;
    const float* wrow = W + (long long)bin * NFFT;
    float s = 0.f;
    const int base = fr * HOPSZ - (NFFT / 2);
    for (int j = 0; j < NFFT; ++j) {
      int xi = base + j;
      float xv = ((unsigned)xi < (unsigned)XLEN) ? xb[xi] : 0.f;
      s = fmaf(xv, wrow[j], s);
    }
    size_t off;
    if (bin < FBIN) off = ((size_t)b * FBIN + bin) * NFRAMES + fr;
    else            off = TOTOUT + ((size_t)b * FBIN + (bin - FBIN)) * NFRAMES + fr;
    out[off] = s;
  }
}

extern "C" void kernel_launch(void* const* d_in, const int* in_sizes, int n_in,
                              void* d_out, int out_size, void* d_ws, size_t ws_size,
                              hipStream_t stream) {
  const float* x = (const float*)d_in[0];
  const float* W = (const float*)d_in[1];
  float* out = (float*)d_out;

  const size_t xp_bytes = (size_t)NBATCH * PADLEN * sizeof(unsigned short);
  const size_t wb_bytes = (size_t)NBINS2 * NFFT * sizeof(unsigned short);

  if (ws_size >= xp_bytes + wb_bytes) {
    unsigned short* xp = (unsigned short*)d_ws;
    unsigned short* wb = (unsigned short*)((char*)d_ws + xp_bytes);

    pack_kernel<<<PX_BLKS + PW_BLKS, 256, 0, stream>>>(x, W, xp, wb);
    stft_mfma128_kernel<<<NWG + TAIL_BLKS, 256, LDS_BYTES, stream>>>(xp, wb, out);
  } else {
    stft_direct_kernel<<<2048, 256, 0, stream>>>(x, W, out, 0, NBINS2, 0, NFRAMES);
  }
}

// Round 17
// 66.057 us; speedup vs baseline: 1.0792x; 1.0792x over previous
//
#include <hip/hip_runtime.h>
#include <hip/hip_bf16.h>

#define NFFT    1024
#define HOPSZ   256
#define XLEN    262144
#define PADLEN  (XLEN + NFFT)      // 263168
#define NBATCH  16
#define NBINS2  1026
#define FBIN    513
#define NFRAMES 1025
#define NGF     (NBATCH * NFRAMES) // 16400
#define TOTOUT  ((size_t)NBATCH * FBIN * NFRAMES)

// GEMM geometry: 128 bins x 128 gf per block, BK=64, 4 waves (2 bin-halves x 2 gf-halves)
#define KT 64
#define NKT 16
#define NWG 1024                   // 8 mt x 128 nt
#define BUFE 16384                 // elems per buffer: W 128x64 + X 128x64
#define BUFB 32768                 // bytes per buffer
#define LDS_BYTES (2 * BUFB)       // 65536 -> 2 blocks/CU
#define NTAIL  49184               // 2*16400 + 16*1024
#define PSTRIDE 132

// fused pack kernel block ranges
#define PX_BLKS 2056               // NBATCH*PADLEN/8/256
#define PW_BLKS 1026               // NBINS2*NFFT/4/256

typedef short bf16x8 __attribute__((ext_vector_type(8)));
typedef float f32x4  __attribute__((ext_vector_type(4)));
typedef unsigned short u16x8 __attribute__((ext_vector_type(8)));
typedef unsigned short u16x4 __attribute__((ext_vector_type(4)));

__device__ __forceinline__ unsigned short f2bf(float f) {
  union { float f; unsigned u; } v; v.f = f;
  unsigned r = v.u + 0x7fffu + ((v.u >> 16) & 1u);   // RNE
  return (unsigned short)(r >> 16);
}
__device__ __forceinline__ float bf2f(unsigned short h) {
  union { unsigned u; float f; } v; v.u = ((unsigned)h) << 16; return v.f;
}

typedef __attribute__((address_space(1))) void void_g;
typedef __attribute__((address_space(3))) void void_l;
__device__ __forceinline__ void gload_lds16(const void* g, void* l) {
  __builtin_amdgcn_global_load_lds((void_g*)(g), (void_l*)(l), 16, 0, 0);
}

// ---- fused pack: x -> bf16 (padded) | W -> bf16 ----
__global__ __launch_bounds__(256) void pack_kernel(const float* __restrict__ x,
                                                   const float* __restrict__ W,
                                                   unsigned short* __restrict__ xp,
                                                   unsigned short* __restrict__ wb) {
  const int bid = blockIdx.x;
  const int tid = threadIdx.x;
  if (bid < PX_BLKS) {
    long long base = ((long long)bid * 256 + tid) * 8;
    int b   = (int)(base / PADLEN);
    int pos = (int)(base % PADLEN);
    const float* xb = x + (long long)b * XLEN;
    u16x8 v;
#pragma unroll
    for (int j = 0; j < 8; ++j) {
      int xi = pos + j - (NFFT / 2);
      float f = ((unsigned)xi < (unsigned)XLEN) ? xb[xi] : 0.0f;
      v[j] = f2bf(f);
    }
    *reinterpret_cast<u16x8*>(xp + base) = v;
  } else {
    long long t = (((long long)(bid - PX_BLKS)) * 256 + tid) * 4;
    float4 f = *reinterpret_cast<const float4*>(W + t);
    u16x4 v;
    v[0] = f2bf(f.x); v[1] = f2bf(f.y); v[2] = f2bf(f.z); v[3] = f2bf(f.w);
    *reinterpret_cast<u16x4*>(wb + t) = v;
  }
}

// ---- 128x128 GEMM, r9 schedule, 2 blocks/CU, X-locality XCD swizzle ----
__global__ __launch_bounds__(256, 2) void stft_mfma128_kernel(const unsigned short* __restrict__ Xp,
                                                              const unsigned short* __restrict__ Wb,
                                                              float* __restrict__ out) {
  extern __shared__ unsigned short lds[];
  const int tid = threadIdx.x;
  const int l   = tid & 63;
  const int w   = tid >> 6;        // 0..3
  const int wr  = w >> 1;          // bin half (64 bins)
  const int wc  = w & 1;           // gf half (64 frames)
  const int r16 = l & 15, hi = l >> 4;

  // XCD swizzle: each XCD owns all 8 mt x 16 nt; consecutive blocks vary mt
  // (share the X slab of one nt) -> X fetched once per XCD, W panels L2-hot.
  const int bid   = blockIdx.x;
  const int xcd   = bid & 7;
  const int local = bid >> 3;           // 0..127
  const int nt    = xcd * 16 + (local >> 3);
  const int mt    = local & 7;
  const int bin0  = mt * 128;
  const int gf0   = nt * 128;

  // staging (pre-swizzled global source)
  const int lr = l >> 3;
  const int ls = l & 7;
  const int cswz = ((ls ^ lr) << 3);

  unsigned aqoff[4], boff[4];
#pragma unroll
  for (int q = 0; q < 4; ++q)
    aqoff[q] = (unsigned)(bin0 + (w * 4 + q) * 8 + lr) * NFFT + cswz;
#pragma unroll
  for (int j = 0; j < 4; ++j) {
    const int gf = gf0 + (w * 4 + j) * 8 + lr;     // < 16384
    const int bb = gf / NFRAMES;
    const int fr = gf - bb * NFRAMES;
    boff[j] = (unsigned)bb * PADLEN + (unsigned)fr * HOPSZ + cswz;
  }

#define STAGE(D, KC) do { \
    _Pragma("unroll") \
    for (int q_ = 0; q_ < 4; ++q_) \
      gload_lds16(Wb + aqoff[q_] + (KC), lds + (D) * BUFE + (w * 4 + q_) * 512); \
    _Pragma("unroll") \
    for (int j_ = 0; j_ < 4; ++j_) \
      gload_lds16(Xp + boff[j_] + (KC), lds + (D) * BUFE + 8192 + (w * 4 + j_) * 512); \
    } while (0)

  // fragment read bases (T2 XOR-swizzle, 128B rows, 8x16B slots)
  const int aB0 = (wr * 64 + r16) * 128;
  const int bB0 = 16384 + (wc * 64 + r16) * 128;
  const int swz = (r16 & 7) << 4;
  const int c0  = (hi * 16) ^ swz;
  const int c1  = (64 + hi * 16) ^ swz;

#define RD8(BASE, C, AARR, BARR) do { \
    _Pragma("unroll") \
    for (int n_ = 0; n_ < 4; ++n_) \
      BARR[n_] = *reinterpret_cast<const bf16x8*>((const char*)(BASE) + bB0 + n_ * 2048 + (C)); \
    _Pragma("unroll") \
    for (int m_ = 0; m_ < 4; ++m_) \
      AARR[m_] = *reinterpret_cast<const bf16x8*>((const char*)(BASE) + aB0 + m_ * 2048 + (C)); \
    } while (0)

#define MFMA16(AARR, BARR) do { \
    __builtin_amdgcn_s_setprio(1); \
    _Pragma("unroll") \
    for (int m_ = 0; m_ < 4; ++m_) { \
      _Pragma("unroll") \
      for (int n_ = 0; n_ < 4; ++n_) \
        acc[m_][n_] = __builtin_amdgcn_mfma_f32_16x16x32_bf16(AARR[m_], BARR[n_], acc[m_][n_], 0, 0, 0); \
    } \
    __builtin_amdgcn_s_setprio(0); } while (0)

  f32x4 acc[4][4] = {};
  bf16x8 A0[4], B0[4], A1[4], B1[4];

  // ---- prologue: stage kt0->buf0, kt1->buf1; kt0 visible; read (buf0,ks0) ----
  STAGE(0, 0);
  STAGE(1, KT);
  asm volatile("s_waitcnt vmcnt(8)" ::: "memory");
  __builtin_amdgcn_s_barrier();
  __builtin_amdgcn_sched_barrier(0);
  RD8(lds, c0, A0, B0);

#pragma unroll 1
  for (int t = 0; t < NKT; ++t) {
    const int ci = t & 1;
    const char* cbuf = (const char*)lds + ci * BUFB;
    const char* nbuf = (const char*)lds + (ci ^ 1) * BUFB;
    const int kc2 = (t + 2) << 6;

    // phase A: read (cbuf, ks1) ahead; counted wait; MFMA ks0
    RD8(cbuf, c1, A1, B1);
    __builtin_amdgcn_sched_barrier(0);
    asm volatile("s_waitcnt lgkmcnt(8)" ::: "memory");
    __builtin_amdgcn_sched_barrier(0);
    MFMA16(A0, B0);

    // phase B: drain own reads+stages BEFORE barrier (cross-wave safety);
    // barrier; next-tile reads + kt+2 stages under MFMA ks1
    asm volatile("s_waitcnt vmcnt(0) lgkmcnt(0)" ::: "memory");
    __builtin_amdgcn_sched_barrier(0);
    __builtin_amdgcn_s_barrier();
    __builtin_amdgcn_sched_barrier(0);
    if (t < NKT - 1) RD8(nbuf, c0, A0, B0);
    if (t < NKT - 2) STAGE(ci, kc2);
    __builtin_amdgcn_sched_barrier(0);
    MFMA16(A1, B1);
  }

  // ---- epilogue: 2 chunks of 64 bin-rows; LDS patch; 256B-contiguous streams ----
  {
    float* patch = (float*)lds;
    const int col   = l & 15;
    const int rbase = (l >> 4) * 4;
    const int colbase = wc * 64;

    size_t baseR[2];
#pragma unroll
    for (int j = 0; j < 2; ++j) {
      const int gf = gf0 + j * 64 + l;
      const int bb = gf / NFRAMES;
      const int fr = gf - bb * NFRAMES;
      baseR[j] = (size_t)bb * FBIN * NFRAMES + fr;
    }

#pragma unroll
    for (int c = 0; c < 2; ++c) {
      __builtin_amdgcn_s_barrier();
      if (wr == c) {
#pragma unroll
        for (int m = 0; m < 4; ++m)
#pragma unroll
          for (int n = 0; n < 4; ++n)
#pragma unroll
            for (int r = 0; r < 4; ++r)
              patch[(m * 16 + rbase + r) * PSTRIDE + colbase + n * 16 + col] = acc[m][n][r];
      }
      __builtin_amdgcn_s_barrier();

      for (int i = 0; i < 16; ++i) {
        const int row = i * 4 + w;
        const int bin = bin0 + c * 64 + row;
        const size_t binoff = (size_t)bin * NFRAMES;
#pragma unroll
        for (int j = 0; j < 2; ++j) {
          const float v = patch[row * PSTRIDE + j * 64 + l];
          size_t off = binoff + (bin < FBIN ? baseR[j]
                                            : baseR[j] + TOTOUT - (size_t)FBIN * NFRAMES);
          out[off] = v;
        }
      }
    }
  }
#undef STAGE
#undef RD8
#undef MFMA16
}

// ---- tail kernel: wave-per-output for leftover bins/frames ----
__global__ __launch_bounds__(512) void stft_tail_kernel(const unsigned short* __restrict__ Xp,
                                                        const unsigned short* __restrict__ Wb,
                                                        float* __restrict__ out) {
  const int wid = (int)((blockIdx.x * 512 + threadIdx.x) >> 6);
  const int l   = threadIdx.x & 63;
  if (wid >= NTAIL) return;
  int bin, gf;
  if (wid < 2 * NGF) { bin = 1024 + (wid & 1); gf = wid >> 1; }
  else { const int s = wid - 2 * NGF; gf = 16384 + (s & 15); bin = s >> 4; }
  const int bb = gf / NFRAMES;
  const int fr = gf - bb * NFRAMES;
  const unsigned short* xr = Xp + (size_t)bb * PADLEN + (size_t)fr * HOPSZ + l * 16;
  const unsigned short* wr = Wb + (size_t)bin * NFFT + l * 16;
  u16x8 x0 = *reinterpret_cast<const u16x8*>(xr);
  u16x8 x1 = *reinterpret_cast<const u16x8*>(xr + 8);
  u16x8 w0 = *reinterpret_cast<const u16x8*>(wr);
  u16x8 w1 = *reinterpret_cast<const u16x8*>(wr + 8);
  float s0 = 0.f, s1 = 0.f;
#pragma unroll
  for (int j = 0; j < 8; ++j) {
    s0 = fmaf(bf2f(x0[j]), bf2f(w0[j]), s0);
    s1 = fmaf(bf2f(x1[j]), bf2f(w1[j]), s1);
  }
  float s = s0 + s1;
#pragma unroll
  for (int k = 32; k >= 1; k >>= 1) s += __shfl_xor(s, k);
  if (l == 0) {
    size_t off;
    if (bin < FBIN) off = ((size_t)bb * FBIN + bin) * NFRAMES + fr;
    else            off = TOTOUT + ((size_t)bb * FBIN + (bin - FBIN)) * NFRAMES + fr;
    out[off] = s;
  }
}

// ---- exact f32 direct kernel: fallback only ----
__global__ void stft_direct_kernel(const float* __restrict__ x, const float* __restrict__ W,
                                   float* __restrict__ out,
                                   int bin_lo, int nbins, int fr_lo, int nframes) {
  long long total = (long long)NBATCH * nbins * nframes;
  for (long long t = (long long)blockIdx.x * blockDim.x + threadIdx.x; t < total;
       t += (long long)gridDim.x * blockDim.x) {
    int fr = fr_lo + (int)(t % nframes);
    long long q = t / nframes;
    int bin = bin_lo + (int)(q % nbins);
    int b   = (int)(q / nbins);
    const float* xb = x + (long long)b * XLEN;
    const float* wrow = W + (long long)bin * NFFT;
    float s = 0.f;
    const int base = fr * HOPSZ - (NFFT / 2);
    for (int j = 0; j < NFFT; ++j) {
      int xi = base + j;
      float xv = ((unsigned)xi < (unsigned)XLEN) ? xb[xi] : 0.f;
      s = fmaf(xv, wrow[j], s);
    }
    size_t off;
    if (bin < FBIN) off = ((size_t)b * FBIN + bin) * NFRAMES + fr;
    else            off = TOTOUT + ((size_t)b * FBIN + (bin - FBIN)) * NFRAMES + fr;
    out[off] = s;
  }
}

extern "C" void kernel_launch(void* const* d_in, const int* in_sizes, int n_in,
                              void* d_out, int out_size, void* d_ws, size_t ws_size,
                              hipStream_t stream) {
  const float* x = (const float*)d_in[0];
  const float* W = (const float*)d_in[1];
  float* out = (float*)d_out;

  const size_t xp_bytes = (size_t)NBATCH * PADLEN * sizeof(unsigned short);
  const size_t wb_bytes = (size_t)NBINS2 * NFFT * sizeof(unsigned short);

  if (ws_size >= xp_bytes + wb_bytes) {
    unsigned short* xp = (unsigned short*)d_ws;
    unsigned short* wb = (unsigned short*)((char*)d_ws + xp_bytes);

    pack_kernel<<<PX_BLKS + PW_BLKS, 256, 0, stream>>>(x, W, xp, wb);
    stft_mfma128_kernel<<<NWG, 256, LDS_BYTES, stream>>>(xp, wb, out);
    stft_tail_kernel<<<NTAIL / 8, 512, 0, stream>>>(xp, wb, out);
  } else {
    stft_direct_kernel<<<2048, 256, 0, stream>>>(x, W, out, 0, NBINS2, 0, NFRAMES);
  }
}